// Round 1
// baseline (402.267 us; speedup 1.0000x reference)
//
#include <hip/hip_runtime.h>

namespace {
constexpr int Bx = 8, Cc = 64, Hh = 128, Ww = 128, Rr = 4, Co = 64;
constexpr int Ll = Hh * Ww;        // 16384 = 2^14
constexpr int NPIX = Bx * Ll;      // 131072
constexpr int NW = 80;             // 4 gate + 12 geom + 64 value outputs per pixel
constexpr int TP = 16;             // pixels per block in k3
}

// ---------------- k0: pack projection weights transposed: wt[c][j] ----------------
__global__ __launch_bounds__(256) void k0_pack_weights(
    const float* __restrict__ gate_w,   // [4][64]
    const float* __restrict__ geom_w,   // [12][64]
    const float* __restrict__ value_w,  // [64][64]
    float* __restrict__ wt)             // [64][80]
{
    for (int idx = threadIdx.x; idx < Cc * NW; idx += 256) {
        int c = idx / NW, j = idx % NW;
        float val;
        if (j < 4)       val = gate_w[j * Cc + c];
        else if (j < 16) val = geom_w[(j - 4) * Cc + c];
        else             val = value_w[(j - 16) * Cc + c];
        wt[idx] = val;
    }
}

__device__ __forceinline__ float softplusf(float v) {
    return v > 20.f ? v : log1pf(__expf(v));
}

// ---------------- k1: per-pixel 1x1 projections ----------------
__global__ __launch_bounds__(256) void k1_project(
    const float* __restrict__ x,       // [B][64][L]
    const float* __restrict__ wt,      // [64][80]
    const float* __restrict__ gate_b,  // [4]
    const float* __restrict__ geom_b,  // [12]
    float* __restrict__ v,             // [B][L][64]  (pixel-major)
    float* __restrict__ mu,            // [B][4][L]
    float* __restrict__ cs2, float* __restrict__ sn2,
    float* __restrict__ bse, float* __restrict__ hyp)  // each [B][4][L]
{
    const int tid = threadIdx.x;
    const int pix0 = blockIdx.x * 256;
    const int pix = pix0 + tid;
    const int b = pix >> 14;
    const int l = pix & (Ll - 1);
    const int l0 = pix0 & (Ll - 1);

    float acc[NW];
#pragma unroll
    for (int j = 0; j < NW; ++j) acc[j] = 0.f;

    const float* xb = x + (size_t)b * Cc * Ll + l;
    for (int c = 0; c < Cc; ++c) {
        float xv = xb[(size_t)c * Ll];              // coalesced across lanes
        const float* w = wt + c * NW;               // wave-uniform -> s_load
#pragma unroll
        for (int j = 0; j < NW; ++j) acc[j] = fmaf(w[j], xv, acc[j]);
    }

    // gate softmax over R=4
    float ge[4]; float gm = -1e30f;
#pragma unroll
    for (int r = 0; r < 4; ++r) { ge[r] = acc[r] + gate_b[r]; gm = fmaxf(gm, ge[r]); }
    float gs = 0.f;
#pragma unroll
    for (int r = 0; r < 4; ++r) { ge[r] = __expf(ge[r] - gm); gs += ge[r]; }
    float ginv = 1.f / gs;

#pragma unroll
    for (int r = 0; r < 4; ++r) {
        size_t fi = ((size_t)b * 4 + r) * Ll + l;
        mu[fi] = ge[r] * ginv;
        float th = acc[4 + r] + geom_b[r];
        float sv, cv;
        __sincosf(2.f * th, &sv, &cv);
        cs2[fi] = cv;
        sn2[fi] = sv;
        bse[fi] = softplusf(acc[8 + r]  + geom_b[4 + r]) + 1e-4f;
        hyp[fi] = softplusf(acc[12 + r] + geom_b[8 + r]);
    }

    // v: transpose to pixel-major [B][L][64] through LDS (64B-segment writes)
    __shared__ float vlds[256 * 17];
    const size_t vbase = ((size_t)b * Ll + l0) * 64;
#pragma unroll
    for (int c0 = 0; c0 < 64; c0 += 16) {
        __syncthreads();
#pragma unroll
        for (int j = 0; j < 16; ++j) vlds[tid * 17 + j] = acc[16 + c0 + j];
        __syncthreads();
#pragma unroll
        for (int k = 0; k < 16; ++k) {
            int flat = k * 256 + tid;
            int p = flat >> 4, j = flat & 15;
            v[vbase + (size_t)p * 64 + c0 + j] = vlds[p * 17 + j];
        }
    }
}

// ---------------- k2: normalized geometry*membership weights w[B][36][L] ----------------
__global__ __launch_bounds__(256) void k2_weights(
    const float* __restrict__ mu,
    const float* __restrict__ cs2, const float* __restrict__ sn2,
    const float* __restrict__ bse, const float* __restrict__ hyp,
    float* __restrict__ wq)            // [B][36][L], rs = r*9+s
{
    const int pix = blockIdx.x * 256 + threadIdx.x;
    const int b = pix >> 14;
    const int l = pix & (Ll - 1);
    const int hr = l >> 7;
    const int wc = l & (Ww - 1);

#pragma unroll
    for (int r = 0; r < 4; ++r) {
        const size_t ci = ((size_t)b * 4 + r) * Ll + l;
        const float cc = cs2[ci], sc = sn2[ci], bc = bse[ci], yc = hyp[ci];
        float cmp[9];
        float sum = 0.f;
#pragma unroll
        for (int s = 0; s < 9; ++s) {
            const int dy = s / 3 - 1, dx = s % 3 - 1;
            const int hh = hr + dy, ww = wc + dx;
            float cv = 0.f;
            if ((unsigned)hh < (unsigned)Hh && (unsigned)ww < (unsigned)Ww) {
                const size_t ni = ((size_t)b * 4 + r) * Ll + hh * Ww + ww;
                const float cn = cs2[ni], sn = sn2[ni];
                const float bn = bse[ni], yn = hyp[ni], mun = mu[ni];
                const float c2 = cc + cn, s2 = sc + sn;
                const float h2 = sqrtf(c2 * c2 + s2 * s2);
                float ux, uy;
                if (h2 > 0.f) {
                    const float inv = 0.5f / h2;
                    ux = sqrtf(fmaxf((h2 + c2) * inv, 0.f));
                    uy = copysignf(sqrtf(fmaxf((h2 - c2) * inv, 0.f)), s2);
                } else { ux = 1.f; uy = 0.f; }
                const float bp = 0.5f * (bc + bn);
                const float hp = 0.5f * (yc + yn);
                const float e = __expf(hp);
                const float su = bp * e;
                const float ss = bp / e;
                const float dxf = (float)dx, dyf = (float)dy;
                const float pu = ux * dxf + uy * dyf;
                const float ps = ux * dyf - uy * dxf;
                const float q = (pu * pu) / (su * su) + (ps * ps) / (ss * ss);
                cv = __expf(-q) * mun;
            }
            cmp[s] = cv;
            sum += cv;
        }
        const float inv = 1.f / (sum + 1e-6f);
#pragma unroll
        for (int s = 0; s < 9; ++s)
            wq[((size_t)b * 36 + r * 9 + s) * Ll + l] = cmp[s] * inv;
    }
}

// ---------------- k3: fused neighbor aggregation + 1x1 pointwise ----------------
__global__ __launch_bounds__(256) void k3_agg_pw(
    const float* __restrict__ wq,    // [B][36][L]
    const float* __restrict__ v,     // [B][L][64]
    const float* __restrict__ pw_w,  // [64][256]
    const float* __restrict__ pw_b,  // [64]
    float* __restrict__ out)         // [B][64][L]
{
    __shared__ float agg[TP][260];   // stride 260: kills 4-way bank conflict in phase 2
    const int tid = threadIdx.x;
    const int pix0 = blockIdx.x * TP;
    const int b = pix0 >> 14;
    const int l0 = pix0 & (Ll - 1);
    const int hr = l0 >> 7;          // whole tile in one row (W%TP==0)
    const int w0 = l0 & (Ww - 1);
    const int r = tid >> 6, c = tid & 63;

    const float* vb = v + ((size_t)b * Ll) * 64 + c;
    const float* wb = wq + ((size_t)b * 36 + r * 9) * Ll;

    // phase 1: agg[p][m=r*64+c] = sum_s w[r][s][l] * v[c][n_s(l)]
    for (int p = 0; p < TP; ++p) {
        const int l = l0 + p;
        float acc = 0.f;
#pragma unroll
        for (int s = 0; s < 9; ++s) {
            const int dy = s / 3 - 1, dx = s % 3 - 1;
            const int hh = hr + dy, ww = w0 + p + dx;
            if ((unsigned)hh < (unsigned)Hh && (unsigned)ww < (unsigned)Ww) {
                const float wv = wb[(size_t)s * Ll + l];            // broadcast
                acc = fmaf(wv, vb[(size_t)(hh * Ww + ww) * 64], acc); // coalesced
            }
        }
        agg[p][tid] = acc;
    }
    __syncthreads();

    // phase 2: out[o][p] = pw_b[o] + sum_m pw_w[o][m]*agg[p][m]
    const int o = tid >> 2, pg = tid & 3;
    const float4* pwrow = reinterpret_cast<const float4*>(pw_w + o * 256);
    float res[4];
#pragma unroll
    for (int k = 0; k < 4; ++k) {
        const int p = pg + 4 * k;
        float acc = 0.f;
        for (int m4 = 0; m4 < 64; ++m4) {
            const float4 wv = pwrow[m4];
            const float* a = &agg[p][m4 * 4];
            acc = fmaf(wv.x, a[0], acc);
            acc = fmaf(wv.y, a[1], acc);
            acc = fmaf(wv.z, a[2], acc);
            acc = fmaf(wv.w, a[3], acc);
        }
        res[k] = acc + pw_b[o];
    }
    __syncthreads();

    // write via LDS transpose -> 64B-segment stores
    float* olds = &agg[0][0];
#pragma unroll
    for (int k = 0; k < 4; ++k) olds[o * TP + pg + 4 * k] = res[k];
    __syncthreads();
#pragma unroll
    for (int k = 0; k < 4; ++k) {
        const int flat = k * 256 + tid;
        const int oo = flat >> 4, pp = flat & 15;
        out[((size_t)b * Co + oo) * Ll + l0 + pp] = olds[flat];
    }
}

// ---------------- launch ----------------
extern "C" void kernel_launch(void* const* d_in, const int* in_sizes, int n_in,
                              void* d_out, int out_size, void* d_ws, size_t ws_size,
                              hipStream_t stream)
{
    const float* x       = (const float*)d_in[0];
    const float* gate_w  = (const float*)d_in[1];
    const float* gate_b  = (const float*)d_in[2];
    const float* value_w = (const float*)d_in[3];
    const float* geom_w  = (const float*)d_in[4];
    const float* geom_b  = (const float*)d_in[5];
    const float* pw_w    = (const float*)d_in[6];
    const float* pw_b    = (const float*)d_in[7];
    float* out = (float*)d_out;

    float* ws  = (float*)d_ws;
    float* v    = ws;                                  // B*L*64   = 8388608
    float* mu   = v    + (size_t)Bx * Ll * 64;         // B*4*L    = 524288
    float* cs2  = mu   + (size_t)Bx * 4 * Ll;
    float* sn2  = cs2  + (size_t)Bx * 4 * Ll;
    float* bse  = sn2  + (size_t)Bx * 4 * Ll;
    float* hyp  = bse  + (size_t)Bx * 4 * Ll;
    float* wq   = hyp  + (size_t)Bx * 4 * Ll;          // B*36*L   = 4718592
    float* wt   = wq   + (size_t)Bx * 36 * Ll;         // 64*80    = 5120
    // total ws: 15,733,760 floats ~= 63 MB

    k0_pack_weights<<<1, 256, 0, stream>>>(gate_w, geom_w, value_w, wt);
    k1_project<<<NPIX / 256, 256, 0, stream>>>(x, wt, gate_b, geom_b,
                                               v, mu, cs2, sn2, bse, hyp);
    k2_weights<<<NPIX / 256, 256, 0, stream>>>(mu, cs2, sn2, bse, hyp, wq);
    k3_agg_pw<<<NPIX / TP, 256, 0, stream>>>(wq, v, pw_w, pw_b, out);
}

// Round 2
// 159.932 us; speedup vs baseline: 2.5152x; 2.5152x over previous
//
#include <hip/hip_runtime.h>

namespace {
constexpr int Bx = 8, Cc = 64, Hh = 128, Ww = 128, Co = 64;
constexpr int Ll = Hh * Ww;        // 16384 = 2^14
constexpr int NPIX = Bx * Ll;      // 131072
constexpr int NW = 80;             // 4 gate + 12 geom + 64 value outputs per pixel
constexpr int TP = 16;             // pixels per block in k3
}

using short8 = __attribute__((ext_vector_type(8))) short;
using f32x4  = __attribute__((ext_vector_type(4))) float;

__device__ __forceinline__ unsigned short f32_to_bf16(float f) {
    union { float f; unsigned u; } un; un.f = f;
    unsigned r = un.u + 0x7FFFu + ((un.u >> 16) & 1u);   // round-to-nearest-even
    return (unsigned short)(r >> 16);
}

// ---------------- k0: pack projection weights transposed + pw_w -> bf16 ----------------
__global__ __launch_bounds__(256) void k0_pack_weights(
    const float* __restrict__ gate_w,   // [4][64]
    const float* __restrict__ geom_w,   // [12][64]
    const float* __restrict__ value_w,  // [64][64]
    const float* __restrict__ pw_w,     // [64][256]
    float* __restrict__ wt,             // [64][80]
    unsigned short* __restrict__ pwb16) // [64][256] bf16
{
    for (int idx = threadIdx.x; idx < Cc * NW; idx += 256) {
        int c = idx / NW, j = idx % NW;
        float val;
        if (j < 4)       val = gate_w[j * Cc + c];
        else if (j < 16) val = geom_w[(j - 4) * Cc + c];
        else             val = value_w[(j - 16) * Cc + c];
        wt[idx] = val;
    }
    for (int idx = threadIdx.x; idx < Co * 256; idx += 256)
        pwb16[idx] = f32_to_bf16(pw_w[idx]);
}

__device__ __forceinline__ float softplusf(float v) {
    return v > 20.f ? v : log1pf(__expf(v));
}

// ---------------- k1: per-pixel 1x1 projections ----------------
__global__ __launch_bounds__(256) void k1_project(
    const float* __restrict__ x,       // [B][64][L]
    const float* __restrict__ wt,      // [64][80]
    const float* __restrict__ gate_b,  // [4]
    const float* __restrict__ geom_b,  // [12]
    float* __restrict__ v,             // [B][L][64]  (pixel-major)
    float* __restrict__ mu,            // [B][4][L]
    float* __restrict__ cs2, float* __restrict__ sn2,
    float* __restrict__ bse, float* __restrict__ hyp)  // each [B][4][L]
{
    const int tid = threadIdx.x;
    const int pix0 = blockIdx.x * 256;
    const int pix = pix0 + tid;
    const int b = pix >> 14;
    const int l = pix & (Ll - 1);
    const int l0 = pix0 & (Ll - 1);

    float acc[NW];
#pragma unroll
    for (int j = 0; j < NW; ++j) acc[j] = 0.f;

    const float* xb = x + (size_t)b * Cc * Ll + l;
    for (int c = 0; c < Cc; ++c) {
        float xv = xb[(size_t)c * Ll];              // coalesced across lanes
        const float* w = wt + c * NW;               // wave-uniform -> s_load
#pragma unroll
        for (int j = 0; j < NW; ++j) acc[j] = fmaf(w[j], xv, acc[j]);
    }

    // gate softmax over R=4
    float ge[4]; float gm = -1e30f;
#pragma unroll
    for (int r = 0; r < 4; ++r) { ge[r] = acc[r] + gate_b[r]; gm = fmaxf(gm, ge[r]); }
    float gs = 0.f;
#pragma unroll
    for (int r = 0; r < 4; ++r) { ge[r] = __expf(ge[r] - gm); gs += ge[r]; }
    float ginv = 1.f / gs;

#pragma unroll
    for (int r = 0; r < 4; ++r) {
        size_t fi = ((size_t)b * 4 + r) * Ll + l;
        mu[fi] = ge[r] * ginv;
        float th = acc[4 + r] + geom_b[r];
        float sv, cv;
        __sincosf(2.f * th, &sv, &cv);
        cs2[fi] = cv;
        sn2[fi] = sv;
        bse[fi] = softplusf(acc[8 + r]  + geom_b[4 + r]) + 1e-4f;
        hyp[fi] = softplusf(acc[12 + r] + geom_b[8 + r]);
    }

    // v: transpose to pixel-major [B][L][64] through LDS (64B-segment writes)
    __shared__ float vlds[256 * 17];
    const size_t vbase = ((size_t)b * Ll + l0) * 64;
#pragma unroll
    for (int c0 = 0; c0 < 64; c0 += 16) {
        __syncthreads();
#pragma unroll
        for (int j = 0; j < 16; ++j) vlds[tid * 17 + j] = acc[16 + c0 + j];
        __syncthreads();
#pragma unroll
        for (int k = 0; k < 16; ++k) {
            int flat = k * 256 + tid;
            int p = flat >> 4, j = flat & 15;
            v[vbase + (size_t)p * 64 + c0 + j] = vlds[p * 17 + j];
        }
    }
}

// ---------------- k2: normalized geometry*membership weights w[B][36][L] ----------------
__global__ __launch_bounds__(256) void k2_weights(
    const float* __restrict__ mu,
    const float* __restrict__ cs2, const float* __restrict__ sn2,
    const float* __restrict__ bse, const float* __restrict__ hyp,
    float* __restrict__ wq)            // [B][36][L], rs = r*9+s
{
    const int pix = blockIdx.x * 256 + threadIdx.x;
    const int b = pix >> 14;
    const int l = pix & (Ll - 1);
    const int hr = l >> 7;
    const int wc = l & (Ww - 1);

#pragma unroll
    for (int r = 0; r < 4; ++r) {
        const size_t ci = ((size_t)b * 4 + r) * Ll + l;
        const float cc = cs2[ci], sc = sn2[ci], bc = bse[ci], yc = hyp[ci];
        float cmp[9];
        float sum = 0.f;
#pragma unroll
        for (int s = 0; s < 9; ++s) {
            const int dy = s / 3 - 1, dx = s % 3 - 1;
            const int hh = hr + dy, ww = wc + dx;
            float cv = 0.f;
            if ((unsigned)hh < (unsigned)Hh && (unsigned)ww < (unsigned)Ww) {
                const size_t ni = ((size_t)b * 4 + r) * Ll + hh * Ww + ww;
                const float cn = cs2[ni], sn = sn2[ni];
                const float bn = bse[ni], yn = hyp[ni], mun = mu[ni];
                const float c2 = cc + cn, s2 = sc + sn;
                const float h2 = sqrtf(c2 * c2 + s2 * s2);
                float ux, uy;
                if (h2 > 0.f) {
                    const float inv = 0.5f / h2;
                    ux = sqrtf(fmaxf((h2 + c2) * inv, 0.f));
                    uy = copysignf(sqrtf(fmaxf((h2 - c2) * inv, 0.f)), s2);
                } else { ux = 1.f; uy = 0.f; }
                const float bp = 0.5f * (bc + bn);
                const float hp = 0.5f * (yc + yn);
                const float e = __expf(hp);
                const float su = bp * e;
                const float ss = bp / e;
                const float dxf = (float)dx, dyf = (float)dy;
                const float pu = ux * dxf + uy * dyf;
                const float ps = ux * dyf - uy * dxf;
                const float q = (pu * pu) / (su * su) + (ps * ps) / (ss * ss);
                cv = __expf(-q) * mun;
            }
            cmp[s] = cv;
            sum += cv;
        }
        const float inv = 1.f / (sum + 1e-6f);
#pragma unroll
        for (int s = 0; s < 9; ++s)
            wq[((size_t)b * 36 + r * 9 + s) * Ll + l] = cmp[s] * inv;
    }
}

// ---------------- k3: fused neighbor aggregation + MFMA pointwise ----------------
// Phase 1: wave w owns pixels p = w*4..w*4+3; lane c = channel. Each v line is
// loaded ONCE and multiplied by the 4 per-rule weights (was 4x redundant).
// agg stored to LDS as bf16 [p][m], row-padded to 264 (2-way bank conflict = free).
// Phase 2: D[64 o][16 p] = pw_bf16[64][256] x agg[256][16] via
// mfma_f32_16x16x32_bf16; wave w computes o-tile w*16..w*16+15 in 8 k-steps.
__global__ __launch_bounds__(256) void k3_agg_pw(
    const float* __restrict__ wq,            // [B][36][L]
    const float* __restrict__ v,             // [B][L][64]
    const unsigned short* __restrict__ pwb16,// [64][256] bf16
    const float* __restrict__ pw_b,          // [64]
    float* __restrict__ out)                 // [B][64][L]
{
    __shared__ unsigned short agg[TP][264];  // bf16 bits, padded row
    const int tid = threadIdx.x;
    const int w = tid >> 6, c = tid & 63;
    const int pix0 = blockIdx.x * TP;
    const int b = pix0 >> 14;
    const int l0 = pix0 & (Ll - 1);
    const int hr = l0 >> 7;                  // whole tile in one image row
    const int w0 = l0 & (Ww - 1);

    const float* vb  = v  + ((size_t)b * Ll) * 64 + c;
    const float* wqb = wq + (size_t)b * 36 * Ll;

    // phase 1: agg[p][r*64+c] = sum_s wq[r][s][l] * v[c][n_s(l)]
#pragma unroll
    for (int pq = 0; pq < 4; ++pq) {
        const int p = w * 4 + pq;
        const int l = l0 + p;
        float a0 = 0.f, a1 = 0.f, a2 = 0.f, a3 = 0.f;
#pragma unroll
        for (int s = 0; s < 9; ++s) {
            const int dy = s / 3 - 1, dx = s % 3 - 1;
            const int hh = hr + dy, ww2 = w0 + p + dx;
            if ((unsigned)hh < (unsigned)Hh && (unsigned)ww2 < (unsigned)Ww) {
                const float vv = vb[(size_t)(hh * Ww + ww2) * 64];   // coalesced, once
                const float* wr = wqb + (size_t)s * Ll + l;          // wave-uniform
                a0 = fmaf(wr[0],                 vv, a0);
                a1 = fmaf(wr[(size_t) 9 * Ll],   vv, a1);
                a2 = fmaf(wr[(size_t)18 * Ll],   vv, a2);
                a3 = fmaf(wr[(size_t)27 * Ll],   vv, a3);
            }
        }
        agg[p][0 * 64 + c] = f32_to_bf16(a0);
        agg[p][1 * 64 + c] = f32_to_bf16(a1);
        agg[p][2 * 64 + c] = f32_to_bf16(a2);
        agg[p][3 * 64 + c] = f32_to_bf16(a3);
    }
    __syncthreads();

    // phase 2: MFMA. lane layout (16x16x32 bf16):
    //   A[row][k]: row = lane&15, k = (lane>>4)*8 + j   (8 contiguous bf16 = 16B)
    //   B[k][col]: k = (lane>>4)*8 + j, col = lane&15
    //   D[row][col]: col = lane&15, row = (lane>>4)*4 + reg
    const int ar    = tid & 15;
    const int chunk = (tid >> 4) & 3;
    const int o0    = w * 16;
    const unsigned short* aPtr = pwb16 + (o0 + ar) * 256 + chunk * 8;
    const unsigned short* bPtr = &agg[ar][chunk * 8];

    f32x4 d = {0.f, 0.f, 0.f, 0.f};
#pragma unroll
    for (int kt = 0; kt < 8; ++kt) {
        short8 af = *(const short8*)(aPtr + kt * 32);
        short8 bf = *(const short8*)(bPtr + kt * 32);
        d = __builtin_amdgcn_mfma_f32_16x16x32_bf16(af, bf, d, 0, 0, 0);
    }

#pragma unroll
    for (int q = 0; q < 4; ++q) {
        const int o = o0 + chunk * 4 + q;
        out[((size_t)b * Co + o) * Ll + l0 + ar] = d[q] + pw_b[o];
    }
}

// ---------------- launch ----------------
extern "C" void kernel_launch(void* const* d_in, const int* in_sizes, int n_in,
                              void* d_out, int out_size, void* d_ws, size_t ws_size,
                              hipStream_t stream)
{
    const float* x       = (const float*)d_in[0];
    const float* gate_w  = (const float*)d_in[1];
    const float* gate_b  = (const float*)d_in[2];
    const float* value_w = (const float*)d_in[3];
    const float* geom_w  = (const float*)d_in[4];
    const float* geom_b  = (const float*)d_in[5];
    const float* pw_w    = (const float*)d_in[6];
    const float* pw_b    = (const float*)d_in[7];
    float* out = (float*)d_out;

    float* ws  = (float*)d_ws;
    float* v    = ws;                                  // B*L*64   = 8388608
    float* mu   = v    + (size_t)Bx * Ll * 64;         // B*4*L    = 524288
    float* cs2  = mu   + (size_t)Bx * 4 * Ll;
    float* sn2  = cs2  + (size_t)Bx * 4 * Ll;
    float* bse  = sn2  + (size_t)Bx * 4 * Ll;
    float* hyp  = bse  + (size_t)Bx * 4 * Ll;
    float* wq   = hyp  + (size_t)Bx * 4 * Ll;          // B*36*L   = 4718592
    float* wt   = wq   + (size_t)Bx * 36 * Ll;         // 64*80    = 5120
    unsigned short* pwb16 = (unsigned short*)(wt + Cc * NW); // 64*256 bf16 = 32KB
    // total ws: ~63 MB

    k0_pack_weights<<<1, 256, 0, stream>>>(gate_w, geom_w, value_w, pw_w, wt, pwb16);
    k1_project<<<NPIX / 256, 256, 0, stream>>>(x, wt, gate_b, geom_b,
                                               v, mu, cs2, sn2, bse, hyp);
    k2_weights<<<NPIX / 256, 256, 0, stream>>>(mu, cs2, sn2, bse, hyp, wq);
    k3_agg_pw<<<NPIX / TP, 256, 0, stream>>>(wq, v, pwb16, pw_b, out);
}

// Round 3
// 135.324 us; speedup vs baseline: 2.9726x; 1.1818x over previous
//
#include <hip/hip_runtime.h>

namespace {
constexpr int Bx = 8, Cc = 64, Hh = 128, Ww = 128, Co = 64;
constexpr int Ll = Hh * Ww;        // 16384 = 2^14
constexpr int NPIX = Bx * Ll;      // 131072
constexpr int NW = 80;             // 4 gate + 12 geom + 64 value outputs per pixel
constexpr int TP = 16;             // pixels per block in k3
}

using short8 = __attribute__((ext_vector_type(8))) short;
using f32x4  = __attribute__((ext_vector_type(4))) float;

__device__ __forceinline__ unsigned short f32_to_bf16(float f) {
    union { float f; unsigned u; } un; un.f = f;
    unsigned r = un.u + 0x7FFFu + ((un.u >> 16) & 1u);   // round-to-nearest-even
    return (unsigned short)(r >> 16);
}

// ---------------- k0: pack projection weights transposed + pw_w -> bf16 ----------------
__global__ __launch_bounds__(256) void k0_pack_weights(
    const float* __restrict__ gate_w,   // [4][64]
    const float* __restrict__ geom_w,   // [12][64]
    const float* __restrict__ value_w,  // [64][64]
    const float* __restrict__ pw_w,     // [64][256]
    float* __restrict__ wt,             // [64][80]
    unsigned short* __restrict__ pwb16) // [64][256] bf16
{
    for (int idx = threadIdx.x; idx < Cc * NW; idx += 256) {
        int c = idx / NW, j = idx % NW;
        float val;
        if (j < 4)       val = gate_w[j * Cc + c];
        else if (j < 16) val = geom_w[(j - 4) * Cc + c];
        else             val = value_w[(j - 16) * Cc + c];
        wt[idx] = val;
    }
    for (int idx = threadIdx.x; idx < Co * 256; idx += 256)
        pwb16[idx] = f32_to_bf16(pw_w[idx]);
}

__device__ __forceinline__ float softplusf(float v) {
    return v > 20.f ? v : log1pf(__expf(v));
}

// ---------------- k1: per-pixel 1x1 projections ----------------
__global__ __launch_bounds__(256) void k1_project(
    const float* __restrict__ x,       // [B][64][L]
    const float* __restrict__ wt,      // [64][80]
    const float* __restrict__ gate_b,  // [4]
    const float* __restrict__ geom_b,  // [12]
    float* __restrict__ v,             // [B][L][64]  (pixel-major)
    float* __restrict__ mu,            // [B][4][L]
    float* __restrict__ cs2, float* __restrict__ sn2,
    float* __restrict__ bse, float* __restrict__ hyp)  // each [B][4][L]
{
    const int tid = threadIdx.x;
    const int pix0 = blockIdx.x * 256;
    const int pix = pix0 + tid;
    const int b = pix >> 14;
    const int l = pix & (Ll - 1);
    const int l0 = pix0 & (Ll - 1);

    float acc[NW];
#pragma unroll
    for (int j = 0; j < NW; ++j) acc[j] = 0.f;

    const float* xb = x + (size_t)b * Cc * Ll + l;
    for (int c = 0; c < Cc; ++c) {
        float xv = xb[(size_t)c * Ll];              // coalesced across lanes
        const float* w = wt + c * NW;               // uniform -> s_load
#pragma unroll
        for (int j = 0; j < NW; ++j) acc[j] = fmaf(w[j], xv, acc[j]);
    }

    // gate softmax over R=4
    float ge[4]; float gm = -1e30f;
#pragma unroll
    for (int r = 0; r < 4; ++r) { ge[r] = acc[r] + gate_b[r]; gm = fmaxf(gm, ge[r]); }
    float gs = 0.f;
#pragma unroll
    for (int r = 0; r < 4; ++r) { ge[r] = __expf(ge[r] - gm); gs += ge[r]; }
    float ginv = 1.f / gs;

#pragma unroll
    for (int r = 0; r < 4; ++r) {
        size_t fi = ((size_t)b * 4 + r) * Ll + l;
        mu[fi] = ge[r] * ginv;
        float th = acc[4 + r] + geom_b[r];
        float sv, cv;
        __sincosf(2.f * th, &sv, &cv);
        cs2[fi] = cv;
        sn2[fi] = sv;
        bse[fi] = softplusf(acc[8 + r]  + geom_b[4 + r]) + 1e-4f;
        hyp[fi] = softplusf(acc[12 + r] + geom_b[8 + r]);
    }

    // v: transpose to pixel-major [B][L][64] through LDS (64B-segment writes)
    __shared__ float vlds[256 * 17];
    const size_t vbase = ((size_t)b * Ll + l0) * 64;
#pragma unroll
    for (int c0 = 0; c0 < 64; c0 += 16) {
        __syncthreads();
#pragma unroll
        for (int j = 0; j < 16; ++j) vlds[tid * 17 + j] = acc[16 + c0 + j];
        __syncthreads();
#pragma unroll
        for (int k = 0; k < 16; ++k) {
            int flat = k * 256 + tid;
            int p = flat >> 4, j = flat & 15;
            v[vbase + (size_t)p * 64 + c0 + j] = vlds[p * 17 + j];
        }
    }
}

// ---------------- k2: normalized geometry*membership weights ----------------
// Closed-form half-angle: with h = |(c2,s2)|,  ux^2 = 1/2 + c2/2h,
// uy^2 = 1/2 - c2/2h, ux*uy = s2/2h (since h^2 - c2^2 = s2^2, ux >= 0).
// dx,dy in {-1,0,1} compile-time => pu^2/ps^2 are 0-2 FMAs. Branch-free
// clamped loads; OOB masked through mu_n = 0 (matches reference exactly,
// since compat = kern * mu_n and kern is finite).
// Output layout [B][L][36] (t = r*9+s) so k3 reads 9x dwordx4 per pixel.
__global__ __launch_bounds__(256) void k2_weights(
    const float* __restrict__ mu,
    const float* __restrict__ cs2, const float* __restrict__ sn2,
    const float* __restrict__ bse, const float* __restrict__ hyp,
    float* __restrict__ wq)            // [B][L][36]
{
    const int pix = blockIdx.x * 256 + threadIdx.x;
    const int b = pix >> 14;
    const int l = pix & (Ll - 1);
    const int hr = l >> 7;
    const int wc = l & (Ww - 1);

    float cmp[36];
#pragma unroll
    for (int r = 0; r < 4; ++r) {
        const size_t ci = ((size_t)b * 4 + r) * Ll + l;
        const float cc = cs2[ci], sc = sn2[ci], bc = bse[ci], yc = hyp[ci];
        const float mc = mu[ci];
        float sum = 0.f;
#pragma unroll
        for (int s = 0; s < 9; ++s) {
            const int dy = s / 3 - 1, dx = s % 3 - 1;
            float cv;
            if (dx == 0 && dy == 0) {
                cv = mc;                               // q = 0, kern = 1
            } else {
                const int hh = hr + dy, ww = wc + dx;
                const int hcl = min(max(hh, 0), Hh - 1);
                const int wcl = min(max(ww, 0), Ww - 1);
                const bool inb = ((unsigned)hh < (unsigned)Hh) &
                                 ((unsigned)ww < (unsigned)Ww);
                const size_t ni = ((size_t)b * 4 + r) * Ll + hcl * Ww + wcl;
                const float cn = cs2[ni], sn = sn2[ni];
                const float bn = bse[ni], yn = hyp[ni];
                const float mun = inb ? mu[ni] : 0.f;
                const float c2 = cc + cn, s2 = sc + sn;
                const float h = sqrtf(fmaxf(c2 * c2 + s2 * s2, 1e-24f));
                const float rh = __fdividef(0.5f, h);
                float pu2, ps2;
                if (dx != 0 && dy != 0) {              // diagonal: ux^2+uy^2 = 1
                    const float t = 2.f * (float)(dx * dy) * (s2 * rh);
                    pu2 = 1.f + t; ps2 = 1.f - t;
                } else if (dx != 0) {                  // horizontal
                    pu2 = 0.5f + c2 * rh; ps2 = 0.5f - c2 * rh;
                } else {                               // vertical
                    pu2 = 0.5f - c2 * rh; ps2 = 0.5f + c2 * rh;
                }
                const float bp = 0.5f * (bc + bn);
                const float hp = 0.5f * (yc + yn);
                const float E = __expf(hp);
                const float iu = __fdividef(1.f, bp * E);   // 1/sigma_u
                const float is = E * E * iu;                // 1/sigma_s
                const float q = pu2 * (iu * iu) + ps2 * (is * is);
                cv = __expf(-q) * mun;
            }
            cmp[r * 9 + s] = cv;
            sum += cv;
        }
        const float inv = __fdividef(1.f, sum + 1e-6f);
#pragma unroll
        for (int s = 0; s < 9; ++s) cmp[r * 9 + s] *= inv;
    }

    float4* o = (float4*)(wq + ((size_t)b * Ll + l) * 36);
#pragma unroll
    for (int t = 0; t < 9; ++t) {
        float4 f;
        f.x = cmp[4 * t]; f.y = cmp[4 * t + 1];
        f.z = cmp[4 * t + 2]; f.w = cmp[4 * t + 3];
        o[t] = f;
    }
}

// ---------------- k3: fused neighbor aggregation + MFMA pointwise ----------------
// Phase 1 (branch-free): wave w owns pixels p=w*4..w*4+3, lane = channel c.
// The wave's 4 pixels' 3x3 neighborhoods span 3 rows x 6 cols = 18 v-lines,
// loaded once each with clamped addresses (OOB weight is exactly 0).
// wq is [B][L][36]: 9 dwordx4 uniform loads per pixel.
// Phase 2: D[64 o][16 p] = pw_bf16[64][256] x agg_bf16[256][16] via 8x
// mfma_f32_16x16x32_bf16 per wave (wave w -> o-tile w*16..w*16+15).
__global__ __launch_bounds__(256) void k3_agg_pw(
    const float* __restrict__ wq,            // [B][L][36]
    const float* __restrict__ v,             // [B][L][64]
    const unsigned short* __restrict__ pwb16,// [64][256] bf16
    const float* __restrict__ pw_b,          // [64]
    float* __restrict__ out)                 // [B][64][L]
{
    __shared__ unsigned short agg[TP][264];  // bf16 bits, padded row
    const int tid = threadIdx.x;
    const int w = tid >> 6, c = tid & 63;
    const int pix0 = blockIdx.x * TP;
    const int b = pix0 >> 14;
    const int l0 = pix0 & (Ll - 1);
    const int hr = l0 >> 7;                  // whole tile in one image row
    const int w0 = l0 & (Ww - 1);

    const float* vb  = v  + ((size_t)b * Ll) * 64 + c;
    const float* wqb = wq + ((size_t)b * Ll + l0 + w * 4) * 36;

    // 18 shared v-lines for this wave's 4 pixels (clamped rows/cols)
    const int rowb[3] = { max(hr - 1, 0) * Ww, hr * Ww, min(hr + 1, Hh - 1) * Ww };
    const int cbase = w0 + w * 4;
    int colc[6];
#pragma unroll
    for (int i = 0; i < 6; ++i) colc[i] = min(max(cbase + i - 1, 0), Ww - 1);

    float vv[3][6];
#pragma unroll
    for (int ry = 0; ry < 3; ++ry)
#pragma unroll
        for (int cx = 0; cx < 6; ++cx)
            vv[ry][cx] = vb[(size_t)(rowb[ry] + colc[cx]) * 64];

#pragma unroll
    for (int pq = 0; pq < 4; ++pq) {
        const float4* wq4 = (const float4*)(wqb + (size_t)pq * 36);
        float wv[36];
#pragma unroll
        for (int t = 0; t < 9; ++t) {
            const float4 f = wq4[t];
            wv[4 * t] = f.x; wv[4 * t + 1] = f.y;
            wv[4 * t + 2] = f.z; wv[4 * t + 3] = f.w;
        }
        float a0 = 0.f, a1 = 0.f, a2 = 0.f, a3 = 0.f;
#pragma unroll
        for (int s = 0; s < 9; ++s) {
            const float vvv = vv[s / 3][s % 3 + pq];
            a0 = fmaf(wv[s],      vvv, a0);
            a1 = fmaf(wv[9 + s],  vvv, a1);
            a2 = fmaf(wv[18 + s], vvv, a2);
            a3 = fmaf(wv[27 + s], vvv, a3);
        }
        const int p = w * 4 + pq;
        agg[p][0 * 64 + c] = f32_to_bf16(a0);
        agg[p][1 * 64 + c] = f32_to_bf16(a1);
        agg[p][2 * 64 + c] = f32_to_bf16(a2);
        agg[p][3 * 64 + c] = f32_to_bf16(a3);
    }
    __syncthreads();

    // phase 2: MFMA 16x16x32 bf16
    const int ar    = tid & 15;
    const int chunk = (tid >> 4) & 3;
    const int o0    = w * 16;
    const unsigned short* aPtr = pwb16 + (o0 + ar) * 256 + chunk * 8;
    const unsigned short* bPtr = &agg[ar][chunk * 8];

    f32x4 d = {0.f, 0.f, 0.f, 0.f};
#pragma unroll
    for (int kt = 0; kt < 8; ++kt) {
        short8 af = *(const short8*)(aPtr + kt * 32);
        short8 bf = *(const short8*)(bPtr + kt * 32);
        d = __builtin_amdgcn_mfma_f32_16x16x32_bf16(af, bf, d, 0, 0, 0);
    }

#pragma unroll
    for (int q = 0; q < 4; ++q) {
        const int o = o0 + chunk * 4 + q;
        out[((size_t)b * Co + o) * Ll + l0 + ar] = d[q] + pw_b[o];
    }
}

// ---------------- launch ----------------
extern "C" void kernel_launch(void* const* d_in, const int* in_sizes, int n_in,
                              void* d_out, int out_size, void* d_ws, size_t ws_size,
                              hipStream_t stream)
{
    const float* x       = (const float*)d_in[0];
    const float* gate_w  = (const float*)d_in[1];
    const float* gate_b  = (const float*)d_in[2];
    const float* value_w = (const float*)d_in[3];
    const float* geom_w  = (const float*)d_in[4];
    const float* geom_b  = (const float*)d_in[5];
    const float* pw_w    = (const float*)d_in[6];
    const float* pw_b    = (const float*)d_in[7];
    float* out = (float*)d_out;

    float* ws  = (float*)d_ws;
    float* v    = ws;                                  // B*L*64   = 8388608
    float* mu   = v    + (size_t)Bx * Ll * 64;         // B*4*L    = 524288
    float* cs2  = mu   + (size_t)Bx * 4 * Ll;
    float* sn2  = cs2  + (size_t)Bx * 4 * Ll;
    float* bse  = sn2  + (size_t)Bx * 4 * Ll;
    float* hyp  = bse  + (size_t)Bx * 4 * Ll;
    float* wq   = hyp  + (size_t)Bx * 4 * Ll;          // B*L*36   = 4718592
    float* wt   = wq   + (size_t)Bx * Ll * 36;         // 64*80    = 5120
    unsigned short* pwb16 = (unsigned short*)(wt + Cc * NW); // 64*256 bf16
    // total ws: ~63 MB

    k0_pack_weights<<<1, 256, 0, stream>>>(gate_w, geom_w, value_w, pw_w, wt, pwb16);
    k1_project<<<NPIX / 256, 256, 0, stream>>>(x, wt, gate_b, geom_b,
                                               v, mu, cs2, sn2, bse, hyp);
    k2_weights<<<NPIX / 256, 256, 0, stream>>>(mu, cs2, sn2, bse, hyp, wq);
    k3_agg_pw<<<NPIX / TP, 256, 0, stream>>>(wq, v, pwb16, pw_b, out);
}

// Round 4
// 125.356 us; speedup vs baseline: 3.2090x; 1.0795x over previous
//
#include <hip/hip_runtime.h>

namespace {
constexpr int Bx = 8, Cc = 64, Hh = 128, Ww = 128, Co = 64;
constexpr int Ll = Hh * Ww;        // 16384 = 2^14
constexpr int NPIX = Bx * Ll;      // 131072
constexpr int NW = 80;             // 4 gate + 12 geom + 64 value outputs per pixel
constexpr int TP = 32;             // pixels per block in k3
}

using short8 = __attribute__((ext_vector_type(8))) short;
using f32x4  = __attribute__((ext_vector_type(4))) float;

__device__ __forceinline__ unsigned short f32_to_bf16(float f) {
    union { float f; unsigned u; } un; un.f = f;
    unsigned r = un.u + 0x7FFFu + ((un.u >> 16) & 1u);   // round-to-nearest-even
    return (unsigned short)(r >> 16);
}
__device__ __forceinline__ unsigned pack_bf16x2(float lo, float hi) {
    return (unsigned)f32_to_bf16(lo) | ((unsigned)f32_to_bf16(hi) << 16);
}

// ---------------- k0: pack projection weights transposed + pw_w -> bf16 ----------------
// pwb16 k-order is m' = c*4 + r (matches k3's packed agg writes).
__global__ __launch_bounds__(256) void k0_pack_weights(
    const float* __restrict__ gate_w,   // [4][64]
    const float* __restrict__ geom_w,   // [12][64]
    const float* __restrict__ value_w,  // [64][64]
    const float* __restrict__ pw_w,     // [64][256], m = r*64+c
    float* __restrict__ wt,             // [64][80]
    unsigned short* __restrict__ pwb16) // [64][256] bf16, m' = c*4+r
{
    for (int idx = threadIdx.x; idx < Cc * NW; idx += 256) {
        int c = idx / NW, j = idx % NW;
        float val;
        if (j < 4)       val = gate_w[j * Cc + c];
        else if (j < 16) val = geom_w[(j - 4) * Cc + c];
        else             val = value_w[(j - 16) * Cc + c];
        wt[idx] = val;
    }
    for (int idx = threadIdx.x; idx < Co * 256; idx += 256) {
        const int o = idx >> 8, m = idx & 255;
        const int r = m >> 6, c = m & 63;
        pwb16[o * 256 + c * 4 + r] = f32_to_bf16(pw_w[idx]);
    }
}

__device__ __forceinline__ float softplusf(float v) {
    return v > 20.f ? v : log1pf(__expf(v));
}

// ---------------- k1: per-pixel 1x1 projections ----------------
__global__ __launch_bounds__(256) void k1_project(
    const float* __restrict__ x,       // [B][64][L]
    const float* __restrict__ wt,      // [64][80]
    const float* __restrict__ gate_b,  // [4]
    const float* __restrict__ geom_b,  // [12]
    float* __restrict__ v,             // [B][L][64]  (pixel-major)
    float* __restrict__ mu,            // [B][4][L]
    float* __restrict__ cs2, float* __restrict__ sn2,
    float* __restrict__ bse, float* __restrict__ hyp)  // each [B][4][L]
{
    const int tid = threadIdx.x;
    const int pix0 = blockIdx.x * 256;
    const int pix = pix0 + tid;
    const int b = pix >> 14;
    const int l = pix & (Ll - 1);
    const int l0 = pix0 & (Ll - 1);

    float acc[NW];
#pragma unroll
    for (int j = 0; j < NW; ++j) acc[j] = 0.f;

    const float* xb = x + (size_t)b * Cc * Ll + l;
    for (int c = 0; c < Cc; ++c) {
        float xv = xb[(size_t)c * Ll];              // coalesced across lanes
        const float* w = wt + c * NW;               // uniform -> s_load
#pragma unroll
        for (int j = 0; j < NW; ++j) acc[j] = fmaf(w[j], xv, acc[j]);
    }

    // gate softmax over R=4
    float ge[4]; float gm = -1e30f;
#pragma unroll
    for (int r = 0; r < 4; ++r) { ge[r] = acc[r] + gate_b[r]; gm = fmaxf(gm, ge[r]); }
    float gs = 0.f;
#pragma unroll
    for (int r = 0; r < 4; ++r) { ge[r] = __expf(ge[r] - gm); gs += ge[r]; }
    float ginv = 1.f / gs;

#pragma unroll
    for (int r = 0; r < 4; ++r) {
        size_t fi = ((size_t)b * 4 + r) * Ll + l;
        mu[fi] = ge[r] * ginv;
        float th = acc[4 + r] + geom_b[r];
        float sv, cv;
        __sincosf(2.f * th, &sv, &cv);
        cs2[fi] = cv;
        sn2[fi] = sv;
        bse[fi] = softplusf(acc[8 + r]  + geom_b[4 + r]) + 1e-4f;
        hyp[fi] = softplusf(acc[12 + r] + geom_b[8 + r]);
    }

    // v: transpose to pixel-major [B][L][64] through LDS (64B-segment writes)
    __shared__ float vlds[256 * 17];
    const size_t vbase = ((size_t)b * Ll + l0) * 64;
#pragma unroll
    for (int c0 = 0; c0 < 64; c0 += 16) {
        __syncthreads();
#pragma unroll
        for (int j = 0; j < 16; ++j) vlds[tid * 17 + j] = acc[16 + c0 + j];
        __syncthreads();
#pragma unroll
        for (int k = 0; k < 16; ++k) {
            int flat = k * 256 + tid;
            int p = flat >> 4, j = flat & 15;
            v[vbase + (size_t)p * 64 + c0 + j] = vlds[p * 17 + j];
        }
    }
}

// ---------------- k2: normalized geometry*membership weights ----------------
// Closed-form half-angle (see R3 notes). Output [B][L][36], t = r*9+s.
__global__ __launch_bounds__(256) void k2_weights(
    const float* __restrict__ mu,
    const float* __restrict__ cs2, const float* __restrict__ sn2,
    const float* __restrict__ bse, const float* __restrict__ hyp,
    float* __restrict__ wq)            // [B][L][36]
{
    const int pix = blockIdx.x * 256 + threadIdx.x;
    const int b = pix >> 14;
    const int l = pix & (Ll - 1);
    const int hr = l >> 7;
    const int wc = l & (Ww - 1);

    float cmp[36];
#pragma unroll
    for (int r = 0; r < 4; ++r) {
        const size_t ci = ((size_t)b * 4 + r) * Ll + l;
        const float cc = cs2[ci], sc = sn2[ci], bc = bse[ci], yc = hyp[ci];
        const float mc = mu[ci];
        float sum = 0.f;
#pragma unroll
        for (int s = 0; s < 9; ++s) {
            const int dy = s / 3 - 1, dx = s % 3 - 1;
            float cv;
            if (dx == 0 && dy == 0) {
                cv = mc;                               // q = 0, kern = 1
            } else {
                const int hh = hr + dy, ww = wc + dx;
                const int hcl = min(max(hh, 0), Hh - 1);
                const int wcl = min(max(ww, 0), Ww - 1);
                const bool inb = ((unsigned)hh < (unsigned)Hh) &
                                 ((unsigned)ww < (unsigned)Ww);
                const size_t ni = ((size_t)b * 4 + r) * Ll + hcl * Ww + wcl;
                const float cn = cs2[ni], sn = sn2[ni];
                const float bn = bse[ni], yn = hyp[ni];
                const float mun = inb ? mu[ni] : 0.f;
                const float c2 = cc + cn, s2 = sc + sn;
                const float h = sqrtf(fmaxf(c2 * c2 + s2 * s2, 1e-24f));
                const float rh = __fdividef(0.5f, h);
                float pu2, ps2;
                if (dx != 0 && dy != 0) {              // diagonal
                    const float t = 2.f * (float)(dx * dy) * (s2 * rh);
                    pu2 = 1.f + t; ps2 = 1.f - t;
                } else if (dx != 0) {                  // horizontal
                    pu2 = 0.5f + c2 * rh; ps2 = 0.5f - c2 * rh;
                } else {                               // vertical
                    pu2 = 0.5f - c2 * rh; ps2 = 0.5f + c2 * rh;
                }
                const float bp = 0.5f * (bc + bn);
                const float hp = 0.5f * (yc + yn);
                const float E = __expf(hp);
                const float iu = __fdividef(1.f, bp * E);   // 1/sigma_u
                const float is = E * E * iu;                // 1/sigma_s
                const float q = pu2 * (iu * iu) + ps2 * (is * is);
                cv = __expf(-q) * mun;
            }
            cmp[r * 9 + s] = cv;
            sum += cv;
        }
        const float inv = __fdividef(1.f, sum + 1e-6f);
#pragma unroll
        for (int s = 0; s < 9; ++s) cmp[r * 9 + s] *= inv;
    }

    float4* o = (float4*)(wq + ((size_t)b * Ll + l) * 36);
#pragma unroll
    for (int t = 0; t < 9; ++t) {
        float4 f;
        f.x = cmp[4 * t]; f.y = cmp[4 * t + 1];
        f.z = cmp[4 * t + 2]; f.w = cmp[4 * t + 3];
        o[t] = f;
    }
}

// ---------------- k3: fused neighbor aggregation + MFMA pointwise ----------------
// TP=32 pixels/block, 4 waves. Phase 1: wave w owns pixels w*8..w*8+7 (lane =
// channel c). 30 shared v-lines hoisted; wq double-buffered (9 float4 in
// flight while FMA-ing previous pixel). agg LDS layout [p][m'=c*4+r]: lane c
// writes one packed uint2 (4 bf16) -> conflict-free ds_write_b64.
// Phase 2: wave w -> o-tile w*16; A-frags (pwb16, m'-order) loaded before the
// barrier and reused across the 2 p-tiles; 2 interleaved MFMA chains.
__global__ __launch_bounds__(256, 3) void k3_agg_pw(
    const float* __restrict__ wq,            // [B][L][36]
    const float* __restrict__ v,             // [B][L][64]
    const unsigned short* __restrict__ pwb16,// [64][256] bf16, m'-order
    const float* __restrict__ pw_b,          // [64]
    float* __restrict__ out)                 // [B][64][L]
{
    __shared__ unsigned short agg[TP][264];  // row 528B (16B-aligned)
    const int tid = threadIdx.x;
    const int w = tid >> 6, c = tid & 63;
    const int pix0 = blockIdx.x * TP;
    const int b = pix0 >> 14;
    const int l0 = pix0 & (Ll - 1);
    const int hr = l0 >> 7;                  // whole tile in one image row
    const int w0 = l0 & (Ww - 1);

    const float* vb = v + ((size_t)b * Ll) * 64 + c;

    // 30 shared v-lines for this wave's 8 pixels (clamped rows/cols)
    const int rowb[3] = { max(hr - 1, 0) * Ww, hr * Ww, min(hr + 1, Hh - 1) * Ww };
    const int cbase = w0 + w * 8;
    float vv[3][10];
#pragma unroll
    for (int ry = 0; ry < 3; ++ry)
#pragma unroll
        for (int cx = 0; cx < 10; ++cx) {
            const int col = min(max(cbase + cx - 1, 0), Ww - 1);
            vv[ry][cx] = vb[(size_t)(rowb[ry] + col) * 64];
        }

    const float4* wqp = (const float4*)(wq + ((size_t)b * Ll + l0 + w * 8) * 36);

    float4 cur[9];
#pragma unroll
    for (int t = 0; t < 9; ++t) cur[t] = wqp[t];

#pragma unroll
    for (int pq = 0; pq < 8; ++pq) {
        float4 nxt[9];
        if (pq < 7) {
#pragma unroll
            for (int t = 0; t < 9; ++t) nxt[t] = wqp[(pq + 1) * 9 + t];
        }
        float wv[36];
#pragma unroll
        for (int t = 0; t < 9; ++t) {
            wv[4 * t] = cur[t].x; wv[4 * t + 1] = cur[t].y;
            wv[4 * t + 2] = cur[t].z; wv[4 * t + 3] = cur[t].w;
        }
        float a0 = 0.f, a1 = 0.f, a2 = 0.f, a3 = 0.f;
#pragma unroll
        for (int s = 0; s < 9; ++s) {
            const float vvv = vv[s / 3][s % 3 + pq];
            a0 = fmaf(wv[s],      vvv, a0);
            a1 = fmaf(wv[9 + s],  vvv, a1);
            a2 = fmaf(wv[18 + s], vvv, a2);
            a3 = fmaf(wv[27 + s], vvv, a3);
        }
        uint2 pk;
        pk.x = pack_bf16x2(a0, a1);
        pk.y = pack_bf16x2(a2, a3);
        *((uint2*)(&agg[w * 8 + pq][0]) + c) = pk;     // m' = c*4 + r
#pragma unroll
        for (int t = 0; t < 9; ++t) cur[t] = nxt[t];
    }

    // A fragments: in flight across the barrier
    const int ar    = tid & 15;
    const int chunk = (tid >> 4) & 3;
    const int o0    = w * 16;
    const unsigned short* aPtr = pwb16 + (o0 + ar) * 256 + chunk * 8;
    short8 af[8];
#pragma unroll
    for (int kt = 0; kt < 8; ++kt) af[kt] = *(const short8*)(aPtr + kt * 32);

    __syncthreads();

    // phase 2: two p-tiles, interleaved accumulator chains; bias as C-init
    f32x4 d0, d1;
#pragma unroll
    for (int q = 0; q < 4; ++q) { d0[q] = pw_b[o0 + chunk * 4 + q]; d1[q] = d0[q]; }

    const unsigned short* b0 = &agg[ar][chunk * 8];
    const unsigned short* b1 = &agg[16 + ar][chunk * 8];
#pragma unroll
    for (int kt = 0; kt < 8; ++kt) {
        short8 f0 = *(const short8*)(b0 + kt * 32);
        short8 f1 = *(const short8*)(b1 + kt * 32);
        d0 = __builtin_amdgcn_mfma_f32_16x16x32_bf16(af[kt], f0, d0, 0, 0, 0);
        d1 = __builtin_amdgcn_mfma_f32_16x16x32_bf16(af[kt], f1, d1, 0, 0, 0);
    }

#pragma unroll
    for (int q = 0; q < 4; ++q) {
        const int o = o0 + chunk * 4 + q;
        float* ob = out + ((size_t)b * Co + o) * Ll + l0 + ar;
        ob[0]  = d0[q];
        ob[16] = d1[q];
    }
}

// ---------------- launch ----------------
extern "C" void kernel_launch(void* const* d_in, const int* in_sizes, int n_in,
                              void* d_out, int out_size, void* d_ws, size_t ws_size,
                              hipStream_t stream)
{
    const float* x       = (const float*)d_in[0];
    const float* gate_w  = (const float*)d_in[1];
    const float* gate_b  = (const float*)d_in[2];
    const float* value_w = (const float*)d_in[3];
    const float* geom_w  = (const float*)d_in[4];
    const float* geom_b  = (const float*)d_in[5];
    const float* pw_w    = (const float*)d_in[6];
    const float* pw_b    = (const float*)d_in[7];
    float* out = (float*)d_out;

    float* ws  = (float*)d_ws;
    float* v    = ws;                                  // B*L*64   = 8388608
    float* mu   = v    + (size_t)Bx * Ll * 64;         // B*4*L    = 524288
    float* cs2  = mu   + (size_t)Bx * 4 * Ll;
    float* sn2  = cs2  + (size_t)Bx * 4 * Ll;
    float* bse  = sn2  + (size_t)Bx * 4 * Ll;
    float* hyp  = bse  + (size_t)Bx * 4 * Ll;
    float* wq   = hyp  + (size_t)Bx * 4 * Ll;          // B*L*36   = 4718592
    float* wt   = wq   + (size_t)Bx * Ll * 36;         // 64*80    = 5120
    unsigned short* pwb16 = (unsigned short*)(wt + Cc * NW); // 64*256 bf16
    // total ws: ~63 MB

    k0_pack_weights<<<1, 256, 0, stream>>>(gate_w, geom_w, value_w, pw_w, wt, pwb16);
    k1_project<<<NPIX / 256, 256, 0, stream>>>(x, wt, gate_b, geom_b,
                                               v, mu, cs2, sn2, bse, hyp);
    k2_weights<<<NPIX / 256, 256, 0, stream>>>(mu, cs2, sn2, bse, hyp, wq);
    k3_agg_pw<<<NPIX / TP, 256, 0, stream>>>(wq, v, pwb16, pw_b, out);
}

// Round 5
// 107.393 us; speedup vs baseline: 3.7457x; 1.1673x over previous
//
#include <hip/hip_runtime.h>

namespace {
constexpr int Bx = 8, Cc = 64, Hh = 128, Ww = 128, Co = 64;
constexpr int Ll = Hh * Ww;        // 16384 = 2^14
constexpr int NPIX = Bx * Ll;      // 131072
constexpr int NW = 80;             // 4 gate + 12 geom + 64 value outputs per pixel
constexpr int TP = 64;             // pixels per block in k23
}

using short8 = __attribute__((ext_vector_type(8))) short;
using f32x4  = __attribute__((ext_vector_type(4))) float;

__device__ __forceinline__ unsigned short f32_to_bf16(float f) {
    union { float f; unsigned u; } un; un.f = f;
    unsigned r = un.u + 0x7FFFu + ((un.u >> 16) & 1u);   // round-to-nearest-even
    return (unsigned short)(r >> 16);
}
__device__ __forceinline__ unsigned pack_bf16x2(float lo, float hi) {
    return (unsigned)f32_to_bf16(lo) | ((unsigned)f32_to_bf16(hi) << 16);
}

// ---------------- k0: pack projection weights transposed + pw_w -> bf16 ----------------
// pwb16 k-order is m' = c*4 + r (matches k23's packed agg writes).
__global__ __launch_bounds__(256) void k0_pack_weights(
    const float* __restrict__ gate_w,   // [4][64]
    const float* __restrict__ geom_w,   // [12][64]
    const float* __restrict__ value_w,  // [64][64]
    const float* __restrict__ pw_w,     // [64][256], m = r*64+c
    float* __restrict__ wt,             // [64][80]
    unsigned short* __restrict__ pwb16) // [64][256] bf16, m' = c*4+r
{
    for (int idx = threadIdx.x; idx < Cc * NW; idx += 256) {
        int c = idx / NW, j = idx % NW;
        float val;
        if (j < 4)       val = gate_w[j * Cc + c];
        else if (j < 16) val = geom_w[(j - 4) * Cc + c];
        else             val = value_w[(j - 16) * Cc + c];
        wt[idx] = val;
    }
    for (int idx = threadIdx.x; idx < Co * 256; idx += 256) {
        const int o = idx >> 8, m = idx & 255;
        const int r = m >> 6, c = m & 63;
        pwb16[o * 256 + c * 4 + r] = f32_to_bf16(pw_w[idx]);
    }
}

__device__ __forceinline__ float softplusf(float v) {
    return v > 20.f ? v : log1pf(__expf(v));
}

// ---------------- k1: per-pixel 1x1 projections (8-deep x prefetch) ----------------
__global__ __launch_bounds__(256) void k1_project(
    const float* __restrict__ x,       // [B][64][L]
    const float* __restrict__ wt,      // [64][80]
    const float* __restrict__ gate_b,  // [4]
    const float* __restrict__ geom_b,  // [12]
    float* __restrict__ v,             // [B][L][64]  (pixel-major)
    float* __restrict__ mu,            // [B][4][L]
    float* __restrict__ cs2, float* __restrict__ sn2,
    float* __restrict__ bse, float* __restrict__ hyp)  // each [B][4][L]
{
    const int tid = threadIdx.x;
    const int pix0 = blockIdx.x * 256;
    const int pix = pix0 + tid;
    const int b = pix >> 14;
    const int l = pix & (Ll - 1);
    const int l0 = pix0 & (Ll - 1);

    float acc[NW];
#pragma unroll
    for (int j = 0; j < NW; ++j) acc[j] = 0.f;

    const float* xb = x + (size_t)b * Cc * Ll + l;

    float xp[8];
#pragma unroll
    for (int j = 0; j < 8; ++j) xp[j] = xb[(size_t)j * Ll];

#pragma unroll 1
    for (int c0 = 0; c0 < 64; c0 += 8) {
        float xc[8];
#pragma unroll
        for (int j = 0; j < 8; ++j) xc[j] = xp[j];
        if (c0 + 8 < 64) {
#pragma unroll
            for (int j = 0; j < 8; ++j) xp[j] = xb[(size_t)(c0 + 8 + j) * Ll];
        }
#pragma unroll
        for (int j = 0; j < 8; ++j) {
            const float* w = wt + (c0 + j) * NW;     // uniform -> s_load
#pragma unroll
            for (int jj = 0; jj < NW; ++jj) acc[jj] = fmaf(w[jj], xc[j], acc[jj]);
        }
    }

    // gate softmax over R=4
    float ge[4]; float gm = -1e30f;
#pragma unroll
    for (int r = 0; r < 4; ++r) { ge[r] = acc[r] + gate_b[r]; gm = fmaxf(gm, ge[r]); }
    float gs = 0.f;
#pragma unroll
    for (int r = 0; r < 4; ++r) { ge[r] = __expf(ge[r] - gm); gs += ge[r]; }
    float ginv = 1.f / gs;

#pragma unroll
    for (int r = 0; r < 4; ++r) {
        size_t fi = ((size_t)b * 4 + r) * Ll + l;
        mu[fi] = ge[r] * ginv;
        float th = acc[4 + r] + geom_b[r];
        float sv, cv;
        __sincosf(2.f * th, &sv, &cv);
        cs2[fi] = cv;
        sn2[fi] = sv;
        bse[fi] = softplusf(acc[8 + r]  + geom_b[4 + r]) + 1e-4f;
        hyp[fi] = softplusf(acc[12 + r] + geom_b[8 + r]);
    }

    // v: transpose to pixel-major [B][L][64] through LDS (64B-segment writes)
    __shared__ float vlds[256 * 17];
    const size_t vbase = ((size_t)b * Ll + l0) * 64;
#pragma unroll
    for (int c0 = 0; c0 < 64; c0 += 16) {
        __syncthreads();
#pragma unroll
        for (int j = 0; j < 16; ++j) vlds[tid * 17 + j] = acc[16 + c0 + j];
        __syncthreads();
#pragma unroll
        for (int k = 0; k < 16; ++k) {
            int flat = k * 256 + tid;
            int p = flat >> 4, j = flat & 15;
            v[vbase + (size_t)p * 64 + c0 + j] = vlds[p * 17 + j];
        }
    }
}

// ---------------- k23: fused compat + aggregation + MFMA pointwise ----------------
// TP=64 pixels (one half-row), 256 threads = 4 waves.
// Stage A (lane=pixel): thread (px, r=wave) computes the 9 normalized compat
// weights for its (pixel, rule) — all field loads coalesced, normalization
// thread-local — into LDS wqlds[px][r*12+s] (row 52 floats, 16B-aligned rows).
// Stage B (lane=channel): wave w owns px w*16..+15; 54 hoisted v-lines
// (3 rows x 18 cols, clamped; OOB weight = 0); wq via uniform LDS b128
// broadcasts; 36 FMA/px; packed uint2 agg write (m' = c*4+r).
// Stage C: wave w -> o-tile w*16; A-frags loaded once (pre-barrier issue),
// reused across 4 p-tiles; bias as C-init.
__global__ __launch_bounds__(256) void k23_fused(
    const float* __restrict__ mu,
    const float* __restrict__ cs2, const float* __restrict__ sn2,
    const float* __restrict__ bse, const float* __restrict__ hyp,
    const float* __restrict__ v,             // [B][L][64]
    const unsigned short* __restrict__ pwb16,// [64][256] bf16, m'-order
    const float* __restrict__ pw_b,          // [64]
    float* __restrict__ out)                 // [B][64][L]
{
    __shared__ float wqlds[TP * 52];         // [px][r*12+s], rows 208B
    __shared__ unsigned short agg[TP][264];  // bf16, rows 528B

    const int tid = threadIdx.x;
    const int pix0 = blockIdx.x * TP;
    const int b = pix0 >> 14;
    const int l0 = pix0 & (Ll - 1);

    // ---- stage A: lane = pixel ----
    {
        const int px = tid & 63;
        const int r  = tid >> 6;
        const int l  = l0 + px;
        const int hr = l >> 7;
        const int wc = l & (Ww - 1);
        const size_t fb = ((size_t)b * 4 + r) * Ll;

        const float cc = cs2[fb + l], sc = sn2[fb + l];
        const float bc = bse[fb + l], yc = hyp[fb + l];
        const float mc = mu[fb + l];

        float cmp[9];
        float sum = 0.f;
#pragma unroll
        for (int s = 0; s < 9; ++s) {
            const int dy = s / 3 - 1, dx = s % 3 - 1;
            float cv;
            if (dx == 0 && dy == 0) {
                cv = mc;
            } else {
                const int hh = hr + dy, ww = wc + dx;
                const int hcl = min(max(hh, 0), Hh - 1);
                const int wcl = min(max(ww, 0), Ww - 1);
                const bool inb = ((unsigned)hh < (unsigned)Hh) &
                                 ((unsigned)ww < (unsigned)Ww);
                const size_t ni = fb + hcl * Ww + wcl;
                const float cn = cs2[ni], sn = sn2[ni];
                const float bn = bse[ni], yn = hyp[ni];
                const float mun = inb ? mu[ni] : 0.f;
                const float c2 = cc + cn, s2 = sc + sn;
                const float h = sqrtf(fmaxf(c2 * c2 + s2 * s2, 1e-24f));
                const float rh = __fdividef(0.5f, h);
                float pu2, ps2;
                if (dx != 0 && dy != 0) {              // diagonal
                    const float t = 2.f * (float)(dx * dy) * (s2 * rh);
                    pu2 = 1.f + t; ps2 = 1.f - t;
                } else if (dx != 0) {                  // horizontal
                    pu2 = 0.5f + c2 * rh; ps2 = 0.5f - c2 * rh;
                } else {                               // vertical
                    pu2 = 0.5f - c2 * rh; ps2 = 0.5f + c2 * rh;
                }
                const float bp = 0.5f * (bc + bn);
                const float hp = 0.5f * (yc + yn);
                const float E = __expf(hp);
                const float iu = __fdividef(1.f, bp * E);   // 1/sigma_u
                const float is = E * E * iu;                // 1/sigma_s
                const float q = pu2 * (iu * iu) + ps2 * (is * is);
                cv = __expf(-q) * mun;
            }
            cmp[s] = cv;
            sum += cv;
        }
        const float inv = __fdividef(1.f, sum + 1e-6f);
        float* wrow = &wqlds[px * 52 + r * 12];
#pragma unroll
        for (int s = 0; s < 9; ++s) wrow[s] = cmp[s] * inv;
    }
    __syncthreads();

    // ---- stage B: lane = channel ----
    const int w = tid >> 6, c = tid & 63;
    {
        const int hr0  = l0 >> 7;
        const int rowm = max(hr0 - 1, 0) * Ww;
        const int row0 = hr0 * Ww;
        const int rowp = min(hr0 + 1, Hh - 1) * Ww;
        const int rows[3] = { rowm, row0, rowp };
        const int colbase = (l0 & (Ww - 1)) + w * 16;
        const float* vb = v + ((size_t)b * Ll) * 64 + c;

        float vv[3][18];
#pragma unroll
        for (int ry = 0; ry < 3; ++ry)
#pragma unroll
            for (int cx = 0; cx < 18; ++cx) {
                const int col = min(max(colbase + cx - 1, 0), Ww - 1);
                vv[ry][cx] = vb[(size_t)(rows[ry] + col) * 64];
            }

#pragma unroll
        for (int p = 0; p < 16; ++p) {
            const float* wrow = &wqlds[(w * 16 + p) * 52];
            unsigned pk[2];
#pragma unroll
            for (int r = 0; r < 4; ++r) {
                const float4 w0 = *(const float4*)(wrow + r * 12);      // s0..3
                const float4 w1 = *(const float4*)(wrow + r * 12 + 4);  // s4..7
                const float  w8 = wrow[r * 12 + 8];
                float a;
                a = w0.x * vv[0][p];
                a = fmaf(w0.y, vv[0][p + 1], a);
                a = fmaf(w0.z, vv[0][p + 2], a);
                a = fmaf(w0.w, vv[1][p],     a);
                a = fmaf(w1.x, vv[1][p + 1], a);
                a = fmaf(w1.y, vv[1][p + 2], a);
                a = fmaf(w1.z, vv[2][p],     a);
                a = fmaf(w1.w, vv[2][p + 1], a);
                a = fmaf(w8,   vv[2][p + 2], a);
                if (r & 1) pk[r >> 1] |= (unsigned)f32_to_bf16(a) << 16;
                else       pk[r >> 1]  = (unsigned)f32_to_bf16(a);
            }
            uint2 u; u.x = pk[0]; u.y = pk[1];
            *((uint2*)(&agg[w * 16 + p][0]) + c) = u;   // m' = c*4+r
        }
    }

    // A fragments: issue before the barrier (in flight across it)
    const int ar    = tid & 15;
    const int chunk = (tid >> 4) & 3;
    const int o0    = w * 16;
    const unsigned short* aPtr = pwb16 + (o0 + ar) * 256 + chunk * 8;
    short8 af[8];
#pragma unroll
    for (int kt = 0; kt < 8; ++kt) af[kt] = *(const short8*)(aPtr + kt * 32);

    __syncthreads();

    // ---- stage C: MFMA pointwise, 4 p-tiles, A reused ----
    f32x4 d0, d1, d2, d3;
#pragma unroll
    for (int q = 0; q < 4; ++q) {
        const float bv = pw_b[o0 + chunk * 4 + q];
        d0[q] = bv; d1[q] = bv; d2[q] = bv; d3[q] = bv;
    }
    const unsigned short* b0 = &agg[ 0 + ar][chunk * 8];
    const unsigned short* b1 = &agg[16 + ar][chunk * 8];
    const unsigned short* b2 = &agg[32 + ar][chunk * 8];
    const unsigned short* b3 = &agg[48 + ar][chunk * 8];
#pragma unroll
    for (int kt = 0; kt < 8; ++kt) {
        d0 = __builtin_amdgcn_mfma_f32_16x16x32_bf16(af[kt], *(const short8*)(b0 + kt * 32), d0, 0, 0, 0);
        d1 = __builtin_amdgcn_mfma_f32_16x16x32_bf16(af[kt], *(const short8*)(b1 + kt * 32), d1, 0, 0, 0);
        d2 = __builtin_amdgcn_mfma_f32_16x16x32_bf16(af[kt], *(const short8*)(b2 + kt * 32), d2, 0, 0, 0);
        d3 = __builtin_amdgcn_mfma_f32_16x16x32_bf16(af[kt], *(const short8*)(b3 + kt * 32), d3, 0, 0, 0);
    }

#pragma unroll
    for (int q = 0; q < 4; ++q) {
        const int o = o0 + chunk * 4 + q;
        float* ob = out + ((size_t)b * Co + o) * Ll + l0 + ar;
        ob[0]  = d0[q];
        ob[16] = d1[q];
        ob[32] = d2[q];
        ob[48] = d3[q];
    }
}

// ---------------- launch ----------------
extern "C" void kernel_launch(void* const* d_in, const int* in_sizes, int n_in,
                              void* d_out, int out_size, void* d_ws, size_t ws_size,
                              hipStream_t stream)
{
    const float* x       = (const float*)d_in[0];
    const float* gate_w  = (const float*)d_in[1];
    const float* gate_b  = (const float*)d_in[2];
    const float* value_w = (const float*)d_in[3];
    const float* geom_w  = (const float*)d_in[4];
    const float* geom_b  = (const float*)d_in[5];
    const float* pw_w    = (const float*)d_in[6];
    const float* pw_b    = (const float*)d_in[7];
    float* out = (float*)d_out;

    float* ws  = (float*)d_ws;
    float* v    = ws;                                  // B*L*64   = 8388608
    float* mu   = v    + (size_t)Bx * Ll * 64;         // B*4*L    = 524288
    float* cs2  = mu   + (size_t)Bx * 4 * Ll;
    float* sn2  = cs2  + (size_t)Bx * 4 * Ll;
    float* bse  = sn2  + (size_t)Bx * 4 * Ll;
    float* hyp  = bse  + (size_t)Bx * 4 * Ll;
    float* wt   = hyp  + (size_t)Bx * 4 * Ll;          // 64*80 = 5120
    unsigned short* pwb16 = (unsigned short*)(wt + Cc * NW); // 64*256 bf16
    // total ws: ~44 MB

    k0_pack_weights<<<1, 256, 0, stream>>>(gate_w, geom_w, value_w, pw_w, wt, pwb16);
    k1_project<<<NPIX / 256, 256, 0, stream>>>(x, wt, gate_b, geom_b,
                                               v, mu, cs2, sn2, bse, hyp);
    k23_fused<<<NPIX / TP, 256, 0, stream>>>(mu, cs2, sn2, bse, hyp,
                                             v, pwb16, pw_b, out);
}